// Round 3
// baseline (429.091 us; speedup 1.0000x reference)
//
#include <hip/hip_runtime.h>
#include <math.h>

// GatedSpikingReservoirStep — fp16-single MFMA fused kernel + fp64 fixup.
// Round 9: r1/r2 equivalence proved the compiler inserts its own vmcnt(0)
// before plain-C++ LDS reads of global_load_lds-staged buffers (alias
// paranoia), so both rounds ran a fully-drained pipeline (~1.9us fixed cost
// per K-step, MfmaUtil 11%). Fix: (a) inline-asm ds_read_b128 (opaque to the
// compiler -> no implicit vmcnt), manual lgkmcnt(0)+sched_barrier(0) before
// MFMA (rule 18); (b) BK=64 halves step count 128->64, 32 MFMA/wave/step
// (~700cy compute per step); (c) 2-buffer 1-deep prefetch: stage(s+1) issued
// BEFORE compute(s), vmcnt(0) only at step end -> HBM/L2 latency hides under
// compute. XOR swizzle for 128B-row LDS: chunk' = g ^ (row&7); write side via
// pre-swizzled per-lane global src ((lane&7)^(lane>>3)), read side
// (t*4+quad)^(l16&7); 2-way bank aliasing only. LDS 64KB, 2 blocks/CU
// (grid-capped). Epilogue algebra unchanged (u + acc, two live sets).

#define IDIM 512
#define DDIM 2048
#define MAXD 2560
#define BDIM 4096
#define LIST_CAP 262144
#define BAND 4e-3f

typedef __attribute__((ext_vector_type(4))) float f32x4;
typedef __attribute__((ext_vector_type(8))) _Float16 f16x8;

__device__ __forceinline__ void gld16(const unsigned short* g, unsigned short* l) {
    __builtin_amdgcn_global_load_lds((const __attribute__((address_space(1))) void*)g,
                                     (__attribute__((address_space(3))) void*)l,
                                     16, 0, 0);
}
__device__ __forceinline__ f16x8 dsr(unsigned off) {
    f16x8 r;
    asm volatile("ds_read_b128 %0, %1" : "=v"(r) : "v"(off));
    return r;
}
__device__ __forceinline__ float sigf(float x) { return 1.0f / (1.0f + __expf(-x)); }

// ---------------------------------------------------------------------------
// convert: fp32 -> fp16 for X, S=state[:, :2048], Wc=[Win;Wgate], Wr;
// zero out-pad; zero fixup counter. 20480 blocks x 256 (float4 units).
// ---------------------------------------------------------------------------
__global__ __launch_bounds__(256) void convert_kernel(
    const float* __restrict__ x, const float* __restrict__ state,
    const float* __restrict__ win, const float* __restrict__ wgate,
    const float* __restrict__ wres,
    unsigned short* __restrict__ X16, unsigned short* __restrict__ S16,
    unsigned short* __restrict__ Wc16, unsigned short* __restrict__ Wr16,
    float* __restrict__ out, unsigned* __restrict__ cnt)
{
    int idx = blockIdx.x * 256 + threadIdx.x;
    if (idx == 0) *cnt = 0u;
    float4 v;
    unsigned short* p;
    long off;
    if (idx < 524288) {
        v = ((const float4*)x)[idx];
        p = X16; off = (long)idx * 4;
    } else if (idx < 2621440) {
        int i = idx - 524288;
        int row = i >> 9, c4 = i & 511;
        v = *(const float4*)(state + (long)row * MAXD + c4 * 4);
        p = S16; off = (long)i * 4;
    } else if (idx < 3670016) {
        int i = idx - 2621440;
        v = (i < 262144) ? ((const float4*)win)[i] : ((const float4*)wgate)[i - 262144];
        p = Wc16; off = (long)i * 4;
    } else if (idx < 4718592) {
        int i = idx - 3670016;
        v = ((const float4*)wres)[i];
        p = Wr16; off = (long)i * 4;
    } else {
        int i = idx - 4718592;
        int row = i >> 7, c4 = i & 127;
        *(float4*)(out + (long)row * MAXD + DDIM + c4 * 4) = make_float4(0.f, 0.f, 0.f, 0.f);
        return;
    }
    _Float16 h0 = (_Float16)v.x, h1 = (_Float16)v.y;
    _Float16 h2 = (_Float16)v.z, h3 = (_Float16)v.w;
    ushort4 hv;
    hv.x = *(unsigned short*)&h0; hv.y = *(unsigned short*)&h1;
    hv.z = *(unsigned short*)&h2; hv.w = *(unsigned short*)&h3;
    *(ushort4*)(p + off) = hv;
}

// ---------------------------------------------------------------------------
// fused_step: 5 GEMM phases (virtual K=4096) + gating epilogue, 128x128 tile.
// 4 waves x 64x64 quadrant, acc[4][4], BK=64, 2-buffer 1-deep prefetch,
// asm ds_read_b128 + manual waitcnt. LDS layout per buffer: A[128][64] then
// B[128][64] halfwords, chunk-swizzled (chunk' = g ^ (row&7), 16B chunks).
// ---------------------------------------------------------------------------
__global__ __launch_bounds__(256, 2) void fused_step(
    const unsigned short* __restrict__ X16, const unsigned short* __restrict__ S16,
    const unsigned short* __restrict__ Wc16, const unsigned short* __restrict__ Wr16,
    const float* __restrict__ state, float* __restrict__ out,
    unsigned* __restrict__ cnt, unsigned* __restrict__ list)
{
    __shared__ alignas(16) unsigned short ldsm[32768];   // 64 KiB: 2 x (A 16K + B 16K)
    const int t = threadIdx.x;
    const int wave = t >> 6, lane = t & 63;
    const int wr = wave >> 1, wc = wave & 1;
    const int quad = lane >> 4, l16 = lane & 15;
    const int m0 = blockIdx.y * 128;
    const int n0 = blockIdx.x * 128;

    const unsigned LB = (unsigned)(unsigned long)(__attribute__((address_space(3))) unsigned short*)ldsm;
    // read-side swizzled chunk byte offsets (per lane, t=0 / t=1 k-slabs)
    const int e = l16 & 7;
    const unsigned c0 = (unsigned)((quad ^ e) << 4);
    const unsigned c1 = (unsigned)(((4 + quad) ^ e) << 4);
    // write-side per-lane swizzle: row += lane>>3, chunk = (lane&7)^(lane>>3)
    const int srow = (lane >> 3);
    const int scol = ((lane & 7) ^ srow) * 8;            // halfwords

    f32x4 acc[4][4];
    f32x4 u[4][4];    // sum -> 0.2*tanh(i*sum) -> + 0.8*f*prev  (2 live sets)

    #pragma unroll
    for (int mi = 0; mi < 4; mi++)
        #pragma unroll
        for (int ni = 0; ni < 4; ni++)
            acc[mi][ni] = (f32x4)0.0f;

    auto phase = [&](const unsigned short* Ag, long ldA,
                     const unsigned short* Bg, long ldB, int klen) {
        const int nsteps = klen >> 6;
        const unsigned short* aS = Ag + (long)(wave * 32 + srow) * ldA + scol;
        const unsigned short* bS = Bg + (long)(wave * 32 + srow) * ldB + scol;

        auto stage = [&](int s) {
            const int b = s & 1;
            unsigned short* dA = ldsm + b * 16384 + wave * 2048;   // halfwords
            unsigned short* dB = dA + 8192;
            const long k0 = (long)s << 6;
            #pragma unroll
            for (int j = 0; j < 4; j++) {
                gld16(aS + k0 + (long)j * 8 * ldA, dA + j * 512);
                gld16(bS + k0 + (long)j * 8 * ldB, dB + j * 512);
            }
        };

        stage(0);
        asm volatile("s_waitcnt vmcnt(0)" ::: "memory");
        __builtin_amdgcn_s_barrier();

        for (int s = 0; s < nsteps; s++) {
            if (s + 1 < nsteps) stage(s + 1);
            const unsigned ab = LB + (unsigned)((s & 1) * 32768)
                              + (unsigned)((wr * 64 + l16) * 128);
            const unsigned bb = LB + (unsigned)((s & 1) * 32768) + 16384u
                              + (unsigned)((wc * 64 + l16) * 128);
            #pragma unroll
            for (int ks = 0; ks < 2; ks++) {
                const unsigned ct = ks ? c1 : c0;
                f16x8 af[4], bf[4];
                #pragma unroll
                for (int mi = 0; mi < 4; mi++) af[mi] = dsr(ab + mi * 2048 + ct);
                #pragma unroll
                for (int ni = 0; ni < 4; ni++) bf[ni] = dsr(bb + ni * 2048 + ct);
                asm volatile("s_waitcnt lgkmcnt(0)" ::: "memory");
                __builtin_amdgcn_sched_barrier(0);
                #pragma unroll
                for (int mi = 0; mi < 4; mi++)
                    #pragma unroll
                    for (int ni = 0; ni < 4; ni++)
                        acc[mi][ni] = __builtin_amdgcn_mfma_f32_16x16x32_f16(af[mi], bf[ni], acc[mi][ni], 0, 0, 0);
            }
            if (s + 1 < nsteps) asm volatile("s_waitcnt vmcnt(0)" ::: "memory");
            __builtin_amdgcn_s_barrier();
        }
    };

    // Phase 0: acc = prev @ Wres^T          (K = 2048)
    phase(S16 + (long)m0 * DDIM, DDIM, Wr16 + (long)n0 * DDIM, DDIM, DDIM);
    // Phase 1: acc += X @ Win^T  -> u = ip + rp   (K = 512)
    phase(X16 + (long)m0 * IDIM, IDIM, Wc16 + (long)n0 * IDIM, IDIM, IDIM);
    #pragma unroll
    for (int mi = 0; mi < 4; mi++)
        #pragma unroll
        for (int ni = 0; ni < 4; ni++) { u[mi][ni] = acc[mi][ni]; acc[mi][ni] = (f32x4)0.0f; }

    // Phase 2: acc = X @ Wg_i^T  -> u = 0.2*tanh(sig(acc)*u)
    phase(X16 + (long)m0 * IDIM, IDIM, Wc16 + (long)(DDIM + n0) * IDIM, IDIM, IDIM);
    #pragma unroll
    for (int mi = 0; mi < 4; mi++)
        #pragma unroll
        for (int ni = 0; ni < 4; ni++) {
            #pragma unroll
            for (int r = 0; r < 4; r++)
                u[mi][ni][r] = 0.2f * tanhf(sigf(acc[mi][ni][r]) * u[mi][ni][r]);
            acc[mi][ni] = (f32x4)0.0f;
        }

    // Phase 3: acc = X @ Wg_f^T  -> u += 0.8*sig(acc)*prev
    phase(X16 + (long)m0 * IDIM, IDIM, Wc16 + (long)(2 * DDIM + n0) * IDIM, IDIM, IDIM);
    #pragma unroll
    for (int mi = 0; mi < 4; mi++)
        #pragma unroll
        for (int ni = 0; ni < 4; ni++) {
            #pragma unroll
            for (int r = 0; r < 4; r++) {
                int row = m0 + wr * 64 + mi * 16 + quad * 4 + r;
                int col = n0 + wc * 64 + ni * 16 + l16;
                float prev = state[(long)row * MAXD + col];
                u[mi][ni][r] += 0.8f * sigf(acc[mi][ni][r]) * prev;
            }
            acc[mi][ni] = (f32x4)0.0f;
        }

    // Phase 4: acc = X @ Wg_o^T  -> ns = sig(acc)*u -> spike -> write
    phase(X16 + (long)m0 * IDIM, IDIM, Wc16 + (long)(3 * DDIM + n0) * IDIM, IDIM, IDIM);
    #pragma unroll
    for (int mi = 0; mi < 4; mi++)
        #pragma unroll
        for (int ni = 0; ni < 4; ni++) {
            #pragma unroll
            for (int r = 0; r < 4; r++) {
                int row = m0 + wr * 64 + mi * 16 + quad * 4 + r;
                int col = n0 + wc * 64 + ni * 16 + l16;
                float go = sigf(acc[mi][ni][r]);
                float ns = go * u[mi][ni][r];
                float ov = (ns > 0.5f) ? ns - 0.5f : ns;
                out[(long)row * MAXD + col] = ov;
                if (fabsf(ns - 0.5f) < BAND) {
                    unsigned pos = atomicAdd(cnt, 1u);
                    if (pos < LIST_CAP) list[pos] = (unsigned)(row * DDIM + col);
                }
            }
        }
}

// ---------------------------------------------------------------------------
// fixup: recompute flagged elements exactly in fp64 (inputs are L3-resident).
// ---------------------------------------------------------------------------
__global__ __launch_bounds__(256) void fixup_kernel(
    const float* __restrict__ x, const float* __restrict__ state,
    const float* __restrict__ win, const float* __restrict__ wres,
    const float* __restrict__ wgate,
    const unsigned* __restrict__ cnt, const unsigned* __restrict__ list,
    float* __restrict__ out)
{
    const int gwave = (blockIdx.x * 256 + threadIdx.x) >> 6;
    const int lane = threadIdx.x & 63;
    const int nwaves = gridDim.x * 4;
    unsigned n = *cnt;
    if (n > LIST_CAP) n = LIST_CAP;
    for (unsigned e = gwave; e < n; e += nwaves) {
        unsigned rc = list[e];
        int row = rc >> 11, col = rc & 2047;
        double ip = 0.0, gi = 0.0, gf = 0.0, go = 0.0, rp = 0.0;
        for (int k = lane; k < IDIM; k += 64) {
            double xv = (double)x[(long)row * IDIM + k];
            ip += xv * (double)win[(long)col * IDIM + k];
            gi += xv * (double)wgate[(long)col * IDIM + k];
            gf += xv * (double)wgate[(long)(DDIM + col) * IDIM + k];
            go += xv * (double)wgate[(long)(2 * DDIM + col) * IDIM + k];
        }
        for (int k = lane; k < DDIM; k += 64) {
            rp += (double)state[(long)row * MAXD + k] * (double)wres[(long)col * DDIM + k];
        }
        #pragma unroll
        for (int o = 32; o > 0; o >>= 1) {
            ip += __shfl_down(ip, o);
            gi += __shfl_down(gi, o);
            gf += __shfl_down(gf, o);
            go += __shfl_down(go, o);
            rp += __shfl_down(rp, o);
        }
        if (lane == 0) {
            double si = 1.0 / (1.0 + exp(-gi));
            double sf = 1.0 / (1.0 + exp(-gf));
            double so = 1.0 / (1.0 + exp(-go));
            double prev = (double)state[(long)row * MAXD + col];
            double ns = so * (0.8 * sf * prev + 0.2 * tanh(si * (ip + rp)));
            if (ns > 0.5) ns -= 0.5;
            out[(long)row * MAXD + col] = (float)ns;
        }
    }
}

extern "C" void kernel_launch(void* const* d_in, const int* in_sizes, int n_in,
                              void* d_out, int out_size, void* d_ws, size_t ws_size,
                              hipStream_t stream) {
    const float* x     = (const float*)d_in[0];   // (4096, 512)
    const float* state = (const float*)d_in[1];   // (4096, 2560)
    const float* win   = (const float*)d_in[2];   // (2048, 512)
    const float* wres  = (const float*)d_in[3];   // (2048, 2048)
    const float* wgate = (const float*)d_in[4];   // (6144, 512)
    float* out = (float*)d_out;

    char* ws = (char*)d_ws;
    unsigned short* X16  = (unsigned short*)(ws);                   //  0.. 4 MiB
    unsigned short* S16  = (unsigned short*)(ws + (4ll  << 20));    //  4..20
    unsigned short* Wc16 = (unsigned short*)(ws + (20ll << 20));    // 20..28
    unsigned short* Wr16 = (unsigned short*)(ws + (28ll << 20));    // 28..36
    unsigned* cnt  = (unsigned*)(ws + (36ll << 20));                // 4 B
    unsigned* list = (unsigned*)(ws + (36ll << 20) + 16);           // 1 MiB

    convert_kernel<<<dim3(20480), dim3(256), 0, stream>>>(
        x, state, win, wgate, wres, X16, S16, Wc16, Wr16, out, cnt);

    fused_step<<<dim3(16, 32), dim3(256), 0, stream>>>(
        X16, S16, Wc16, Wr16, state, out, cnt, list);

    fixup_kernel<<<dim3(1024), dim3(256), 0, stream>>>(
        x, state, win, wres, wgate, cnt, list, out);
}

// Round 4
// 406.699 us; speedup vs baseline: 1.0551x; 1.0551x over previous
//
#include <hip/hip_runtime.h>
#include <math.h>

// GatedSpikingReservoirStep — fp16-single MFMA fused kernel + fp64 fixup.
// Round 10: r1/r2/r3 all land at MfmaUtil~11% under 3 different schedules;
// BK doubling didn't move wall time -> not per-barrier overhead. Staging runs
// at ~8 B/cy/CU (1 GB in 242us) vs m97's ~21 B/cy/CU: the vmcnt(0)-per-step
// drain caps in-flight loads (Little's law). Fix = r2's counted vmcnt + r3's
// asm ds_read (which stops the compiler re-inserting drains): 4-buffer BK=32
// rotation, depth-3: iter s issues stage(s+3), computes s, then waits
// vmcnt(8) (s+1 landed; s+2/s+3 in flight ACROSS the barrier; never drain in
// the main loop). LDS 64KB -> 2 blocks/CU preserved. Layout/swizzle = r0's
// measured-conflict-free [128][32] chunk-XOR scheme. Also: fixup loads
// vectorized float4 (was ~360MB of scalar 4B scattered reads).

#define IDIM 512
#define DDIM 2048
#define MAXD 2560
#define BDIM 4096
#define LIST_CAP 262144
#define BAND 4e-3f

typedef __attribute__((ext_vector_type(4))) float f32x4;
typedef __attribute__((ext_vector_type(8))) _Float16 f16x8;

__device__ __forceinline__ void gld16(const unsigned short* g, unsigned short* l) {
    __builtin_amdgcn_global_load_lds((const __attribute__((address_space(1))) void*)g,
                                     (__attribute__((address_space(3))) void*)l,
                                     16, 0, 0);
}
__device__ __forceinline__ f16x8 dsr(unsigned off) {
    f16x8 r;
    asm volatile("ds_read_b128 %0, %1" : "=v"(r) : "v"(off));
    return r;
}
__device__ __forceinline__ float sigf(float x) { return 1.0f / (1.0f + __expf(-x)); }

// ---------------------------------------------------------------------------
// convert: fp32 -> fp16 for X, S=state[:, :2048], Wc=[Win;Wgate], Wr;
// zero out-pad; zero fixup counter. 20480 blocks x 256 (float4 units).
// ---------------------------------------------------------------------------
__global__ __launch_bounds__(256) void convert_kernel(
    const float* __restrict__ x, const float* __restrict__ state,
    const float* __restrict__ win, const float* __restrict__ wgate,
    const float* __restrict__ wres,
    unsigned short* __restrict__ X16, unsigned short* __restrict__ S16,
    unsigned short* __restrict__ Wc16, unsigned short* __restrict__ Wr16,
    float* __restrict__ out, unsigned* __restrict__ cnt)
{
    int idx = blockIdx.x * 256 + threadIdx.x;
    if (idx == 0) *cnt = 0u;
    float4 v;
    unsigned short* p;
    long off;
    if (idx < 524288) {
        v = ((const float4*)x)[idx];
        p = X16; off = (long)idx * 4;
    } else if (idx < 2621440) {
        int i = idx - 524288;
        int row = i >> 9, c4 = i & 511;
        v = *(const float4*)(state + (long)row * MAXD + c4 * 4);
        p = S16; off = (long)i * 4;
    } else if (idx < 3670016) {
        int i = idx - 2621440;
        v = (i < 262144) ? ((const float4*)win)[i] : ((const float4*)wgate)[i - 262144];
        p = Wc16; off = (long)i * 4;
    } else if (idx < 4718592) {
        int i = idx - 3670016;
        v = ((const float4*)wres)[i];
        p = Wr16; off = (long)i * 4;
    } else {
        int i = idx - 4718592;
        int row = i >> 7, c4 = i & 127;
        *(float4*)(out + (long)row * MAXD + DDIM + c4 * 4) = make_float4(0.f, 0.f, 0.f, 0.f);
        return;
    }
    _Float16 h0 = (_Float16)v.x, h1 = (_Float16)v.y;
    _Float16 h2 = (_Float16)v.z, h3 = (_Float16)v.w;
    ushort4 hv;
    hv.x = *(unsigned short*)&h0; hv.y = *(unsigned short*)&h1;
    hv.z = *(unsigned short*)&h2; hv.w = *(unsigned short*)&h3;
    *(ushort4*)(p + off) = hv;
}

// ---------------------------------------------------------------------------
// fused_step: 5 GEMM phases (virtual K=4096) + gating epilogue, 128x128 tile.
// 4 waves x 64x64 quadrant, acc[4][4], BK=32, 4-buffer depth-3 counted-vmcnt
// pipeline, asm ds_read_b128. Per sub-step per wave: 4 gld16 + 8 ds_read +
// 16 MFMA. LDS per buffer: A[128][32] + B[128][32] hw (16 KiB), 4 buffers.
// ---------------------------------------------------------------------------
__global__ __launch_bounds__(256, 2) void fused_step(
    const unsigned short* __restrict__ X16, const unsigned short* __restrict__ S16,
    const unsigned short* __restrict__ Wc16, const unsigned short* __restrict__ Wr16,
    const float* __restrict__ state, float* __restrict__ out,
    unsigned* __restrict__ cnt, unsigned* __restrict__ list)
{
    __shared__ alignas(16) unsigned short ldsm[32768];   // 64 KiB = 4 x 16 KiB buffers
    const int t = threadIdx.x;
    const int wave = t >> 6, lane = t & 63;
    const int wr = wave >> 1, wc = wave & 1;
    const int quad = lane >> 4, l16 = lane & 15;
    const int m0 = blockIdx.y * 128;
    const int n0 = blockIdx.x * 128;
    const int rowoff = lane >> 2;                         // 0..15
    const int kg = ((lane & 3) ^ ((lane >> 3) & 3)) * 8;  // r0's write-side chunk swizzle
    const unsigned krb = (unsigned)((quad ^ ((l16 >> 1) & 3)) << 4);  // read chunk, bytes

    const unsigned LB = (unsigned)(unsigned long)(__attribute__((address_space(3))) unsigned short*)ldsm;
    const unsigned arow = (unsigned)((wr * 64 + l16) * 64) + krb;     // A row base bytes
    const unsigned brow = (unsigned)((wc * 64 + l16) * 64) + krb + 8192u; // B half at +8KB

    f32x4 acc[4][4];
    f32x4 u[4][4];    // sum -> 0.2*tanh(i*sum) -> + 0.8*f*prev  (2 live sets)

    #pragma unroll
    for (int mi = 0; mi < 4; mi++)
        #pragma unroll
        for (int ni = 0; ni < 4; ni++)
            acc[mi][ni] = (f32x4)0.0f;

    auto phase = [&](const unsigned short* Ag, long ldA,
                     const unsigned short* Bg, long ldB, int klen) {
        const int nsteps = klen >> 5;                     // BK=32, nsteps >= 16
        const unsigned short* a0 = Ag + (long)(wave * 32 + rowoff) * ldA + kg;
        const unsigned short* a1 = a0 + (long)16 * ldA;
        const unsigned short* b0 = Bg + (long)(wave * 32 + rowoff) * ldB + kg;
        const unsigned short* b1 = b0 + (long)16 * ldB;

        auto stage = [&](int s) {
            const int b = s & 3;
            unsigned short* dA = ldsm + b * 8192 + wave * 1024;   // halfwords
            unsigned short* dB = dA + 4096;
            const long k0 = (long)s << 5;
            gld16(a0 + k0, dA);
            gld16(a1 + k0, dA + 512);
            gld16(b0 + k0, dB);
            gld16(b1 + k0, dB + 512);
        };

        // prologue: fill 3 buffers; wait for buffer 0 only (vmcnt 8 = stages 1,2 in flight)
        stage(0); stage(1); stage(2);
        asm volatile("s_waitcnt vmcnt(8)" ::: "memory");
        __builtin_amdgcn_s_barrier();

        for (int s = 0; s < nsteps; s++) {
            if (s + 3 < nsteps) stage(s + 3);
            const unsigned bufb = LB + (unsigned)((s & 3) * 16384);
            f16x8 af[4], bf[4];
            #pragma unroll
            for (int mi = 0; mi < 4; mi++) af[mi] = dsr(bufb + arow + mi * 1024);
            #pragma unroll
            for (int ni = 0; ni < 4; ni++) bf[ni] = dsr(bufb + brow + ni * 1024);
            asm volatile("s_waitcnt lgkmcnt(0)" ::: "memory");
            __builtin_amdgcn_sched_barrier(0);
            #pragma unroll
            for (int mi = 0; mi < 4; mi++)
                #pragma unroll
                for (int ni = 0; ni < 4; ni++)
                    acc[mi][ni] = __builtin_amdgcn_mfma_f32_16x16x32_f16(af[mi], bf[ni], acc[mi][ni], 0, 0, 0);
            // counted wait: ensure stage(s+1) landed; keep s+2/s+3 in flight.
            const int rem = nsteps - 2 - s;
            if (rem >= 2)      asm volatile("s_waitcnt vmcnt(8)" ::: "memory");
            else if (rem == 1) asm volatile("s_waitcnt vmcnt(4)" ::: "memory");
            else               asm volatile("s_waitcnt vmcnt(0)" ::: "memory");
            __builtin_amdgcn_s_barrier();
        }
    };

    // Phase 0: acc = prev @ Wres^T          (K = 2048)
    phase(S16 + (long)m0 * DDIM, DDIM, Wr16 + (long)n0 * DDIM, DDIM, DDIM);
    // Phase 1: acc += X @ Win^T  -> u = ip + rp   (K = 512)
    phase(X16 + (long)m0 * IDIM, IDIM, Wc16 + (long)n0 * IDIM, IDIM, IDIM);
    #pragma unroll
    for (int mi = 0; mi < 4; mi++)
        #pragma unroll
        for (int ni = 0; ni < 4; ni++) { u[mi][ni] = acc[mi][ni]; acc[mi][ni] = (f32x4)0.0f; }

    // Phase 2: acc = X @ Wg_i^T  -> u = 0.2*tanh(sig(acc)*u)
    phase(X16 + (long)m0 * IDIM, IDIM, Wc16 + (long)(DDIM + n0) * IDIM, IDIM, IDIM);
    #pragma unroll
    for (int mi = 0; mi < 4; mi++)
        #pragma unroll
        for (int ni = 0; ni < 4; ni++) {
            #pragma unroll
            for (int r = 0; r < 4; r++)
                u[mi][ni][r] = 0.2f * tanhf(sigf(acc[mi][ni][r]) * u[mi][ni][r]);
            acc[mi][ni] = (f32x4)0.0f;
        }

    // Phase 3: acc = X @ Wg_f^T  -> u += 0.8*sig(acc)*prev
    phase(X16 + (long)m0 * IDIM, IDIM, Wc16 + (long)(2 * DDIM + n0) * IDIM, IDIM, IDIM);
    #pragma unroll
    for (int mi = 0; mi < 4; mi++)
        #pragma unroll
        for (int ni = 0; ni < 4; ni++) {
            #pragma unroll
            for (int r = 0; r < 4; r++) {
                int row = m0 + wr * 64 + mi * 16 + quad * 4 + r;
                int col = n0 + wc * 64 + ni * 16 + l16;
                float prev = state[(long)row * MAXD + col];
                u[mi][ni][r] += 0.8f * sigf(acc[mi][ni][r]) * prev;
            }
            acc[mi][ni] = (f32x4)0.0f;
        }

    // Phase 4: acc = X @ Wg_o^T  -> ns = sig(acc)*u -> spike -> write
    phase(X16 + (long)m0 * IDIM, IDIM, Wc16 + (long)(3 * DDIM + n0) * IDIM, IDIM, IDIM);
    #pragma unroll
    for (int mi = 0; mi < 4; mi++)
        #pragma unroll
        for (int ni = 0; ni < 4; ni++) {
            #pragma unroll
            for (int r = 0; r < 4; r++) {
                int row = m0 + wr * 64 + mi * 16 + quad * 4 + r;
                int col = n0 + wc * 64 + ni * 16 + l16;
                float go = sigf(acc[mi][ni][r]);
                float ns = go * u[mi][ni][r];
                float ov = (ns > 0.5f) ? ns - 0.5f : ns;
                out[(long)row * MAXD + col] = ov;
                if (fabsf(ns - 0.5f) < BAND) {
                    unsigned pos = atomicAdd(cnt, 1u);
                    if (pos < LIST_CAP) list[pos] = (unsigned)(row * DDIM + col);
                }
            }
        }
}

// ---------------------------------------------------------------------------
// fixup: recompute flagged elements exactly in fp64, float4-vectorized loads.
// ---------------------------------------------------------------------------
__global__ __launch_bounds__(256) void fixup_kernel(
    const float* __restrict__ x, const float* __restrict__ state,
    const float* __restrict__ win, const float* __restrict__ wres,
    const float* __restrict__ wgate,
    const unsigned* __restrict__ cnt, const unsigned* __restrict__ list,
    float* __restrict__ out)
{
    const int gwave = (blockIdx.x * 256 + threadIdx.x) >> 6;
    const int lane = threadIdx.x & 63;
    const int nwaves = gridDim.x * 4;
    unsigned n = *cnt;
    if (n > LIST_CAP) n = LIST_CAP;
    for (unsigned e = gwave; e < n; e += nwaves) {
        unsigned rc = list[e];
        int row = rc >> 11, col = rc & 2047;
        double ip = 0.0, gi = 0.0, gf = 0.0, go = 0.0, rp = 0.0;
        const float* xr  = x + (long)row * IDIM;
        const float* wi  = win + (long)col * IDIM;
        const float* wgi = wgate + (long)col * IDIM;
        const float* wgf = wgate + (long)(DDIM + col) * IDIM;
        const float* wgo = wgate + (long)(2 * DDIM + col) * IDIM;
        #pragma unroll
        for (int k = lane * 4; k < IDIM; k += 256) {
            float4 xv = *(const float4*)(xr + k);
            float4 a = *(const float4*)(wi + k);
            float4 b = *(const float4*)(wgi + k);
            float4 c = *(const float4*)(wgf + k);
            float4 d = *(const float4*)(wgo + k);
            ip += (double)xv.x * a.x + (double)xv.y * a.y + (double)xv.z * a.z + (double)xv.w * a.w;
            gi += (double)xv.x * b.x + (double)xv.y * b.y + (double)xv.z * b.z + (double)xv.w * b.w;
            gf += (double)xv.x * c.x + (double)xv.y * c.y + (double)xv.z * c.z + (double)xv.w * c.w;
            go += (double)xv.x * d.x + (double)xv.y * d.y + (double)xv.z * d.z + (double)xv.w * d.w;
        }
        const float* sr = state + (long)row * MAXD;
        const float* wr_ = wres + (long)col * DDIM;
        #pragma unroll 2
        for (int k = lane * 4; k < DDIM; k += 256) {
            float4 sv = *(const float4*)(sr + k);
            float4 wv = *(const float4*)(wr_ + k);
            rp += (double)sv.x * wv.x + (double)sv.y * wv.y + (double)sv.z * wv.z + (double)sv.w * wv.w;
        }
        #pragma unroll
        for (int o = 32; o > 0; o >>= 1) {
            ip += __shfl_down(ip, o);
            gi += __shfl_down(gi, o);
            gf += __shfl_down(gf, o);
            go += __shfl_down(go, o);
            rp += __shfl_down(rp, o);
        }
        if (lane == 0) {
            double si = 1.0 / (1.0 + exp(-gi));
            double sf = 1.0 / (1.0 + exp(-gf));
            double so = 1.0 / (1.0 + exp(-go));
            double prev = (double)state[(long)row * MAXD + col];
            double ns = so * (0.8 * sf * prev + 0.2 * tanh(si * (ip + rp)));
            if (ns > 0.5) ns -= 0.5;
            out[(long)row * MAXD + col] = (float)ns;
        }
    }
}

extern "C" void kernel_launch(void* const* d_in, const int* in_sizes, int n_in,
                              void* d_out, int out_size, void* d_ws, size_t ws_size,
                              hipStream_t stream) {
    const float* x     = (const float*)d_in[0];   // (4096, 512)
    const float* state = (const float*)d_in[1];   // (4096, 2560)
    const float* win   = (const float*)d_in[2];   // (2048, 512)
    const float* wres  = (const float*)d_in[3];   // (2048, 2048)
    const float* wgate = (const float*)d_in[4];   // (6144, 512)
    float* out = (float*)d_out;

    char* ws = (char*)d_ws;
    unsigned short* X16  = (unsigned short*)(ws);                   //  0.. 4 MiB
    unsigned short* S16  = (unsigned short*)(ws + (4ll  << 20));    //  4..20
    unsigned short* Wc16 = (unsigned short*)(ws + (20ll << 20));    // 20..28
    unsigned short* Wr16 = (unsigned short*)(ws + (28ll << 20));    // 28..36
    unsigned* cnt  = (unsigned*)(ws + (36ll << 20));                // 4 B
    unsigned* list = (unsigned*)(ws + (36ll << 20) + 16);           // 1 MiB

    convert_kernel<<<dim3(20480), dim3(256), 0, stream>>>(
        x, state, win, wgate, wres, X16, S16, Wc16, Wr16, out, cnt);

    fused_step<<<dim3(16, 32), dim3(256), 0, stream>>>(
        X16, S16, Wc16, Wr16, state, out, cnt, list);

    fixup_kernel<<<dim3(1024), dim3(256), 0, stream>>>(
        x, state, win, wres, wgate, cnt, list, out);
}